// Round 18
// baseline (600.730 us; speedup 1.0000x reference)
//
#include <hip/hip_runtime.h>
#include <stdint.h>

typedef unsigned short u16;
typedef unsigned int u32;
typedef __attribute__((ext_vector_type(8))) short s16x8;
typedef __attribute__((ext_vector_type(4))) float f32x4;

#define P_ 256
#define L_ 64
#define IDIM 512
#define H_ 1024
#define PH (P_ * H_)

__device__ __forceinline__ u16 f2bf(float f){union{float f;u32 u;}v;v.f=f;u32 u=v.u;return (u16)((u+0x7FFFu+((u>>16)&1u))>>16);}
__device__ __forceinline__ float sigf(float x){return 1.0f/(1.0f+__expf(-x));}
__device__ __forceinline__ float tanhf_(float x){return 1.0f-2.0f/(__expf(2.0f*x)+1.0f);}

__device__ __forceinline__ s16x8 pack8v(float4 a, float4 b){
  s16x8 r;
  r[0]=(short)f2bf(a.x); r[1]=(short)f2bf(a.y); r[2]=(short)f2bf(a.z); r[3]=(short)f2bf(a.w);
  r[4]=(short)f2bf(b.x); r[5]=(short)f2bf(b.y); r[6]=(short)f2bf(b.z); r[7]=(short)f2bf(b.w);
  return r;
}
__device__ __forceinline__ s16x8 pack8(const float* s){
  return pack8v(*(const float4*)s, *(const float4*)(s+4));
}
// 16B write-through store (bypasses L2 -> coherent at IF$)
__device__ __forceinline__ void st16_coh(u16* addr, s16x8 v){
  asm volatile("global_store_dwordx4 %0, %1, off sc0 sc1" :: "v"(addr), "v"(v) : "memory");
}
// paired 2-lane bf16 -> one 32-bit write-through store
__device__ __forceinline__ void st_pair(u16* addr, float hv, int lane){
  u32 b = (u32)f2bf(hv);
  u32 other = __shfl_xor(b, 1);
  if ((lane & 1) == 0) {
    u32 w = b | (other << 16);
    __hip_atomic_store((u32*)addr, w, __ATOMIC_RELAXED, __HIP_MEMORY_SCOPE_AGENT);
  }
}
__device__ __forceinline__ void set_flag(u32* f, u32 v){
  __hip_atomic_store(f, v, __ATOMIC_RELAXED, __HIP_MEMORY_SCOPE_AGENT);
}
// block-wide poll: wave0 polls 64 packed flags (one coalesced load/iter) + syncthreads
__device__ __forceinline__ void poll_flags(u32* fg, u32 target, int wid, int lane){
  if (wid == 0) {
    for (;;) {
      u32 f = __hip_atomic_load(&fg[lane], __ATOMIC_RELAXED, __HIP_MEMORY_SCOPE_AGENT);
      if (__all((int)(f >= target))) break;
      __builtin_amdgcn_s_sleep(1);
    }
  }
  asm volatile("" ::: "memory");
  __syncthreads();
}
// lgkm-only barrier (LDS writes drained; VMEM loads stay in flight) — rule #18 fenced
__device__ __forceinline__ void lds_barrier(){
  asm volatile("s_waitcnt lgkmcnt(0)" ::: "memory");
  __builtin_amdgcn_sched_barrier(0);
  __builtin_amdgcn_s_barrier();
  __builtin_amdgcn_sched_barrier(0);
}

// Persistent kernel: 256 blocks x 512 threads = 4 path-groups x 64 unit-blocks.
// 8 waves/block, K-split 192/wave. XCD-clustered (g = bid&3). 128 KB single-round reduce.
// Frozen-path optimization: rows with t >= len skip H stores; consumers read row p
// from Hbuf[min(t, len[p])] (stable address -> L2-resident after freeze).
__global__ void __launch_bounds__(512, 1)
tagger_net(const int* __restrict__ paths, const int* __restrict__ lengths,
           const float* __restrict__ emb,
           const float* __restrict__ Wih, const float* __restrict__ Whh,
           const float* __restrict__ bih, const float* __restrict__ bhh,
           const float* __restrict__ Win, const float* __restrict__ bin,
           const float* __restrict__ Wout, const float* __restrict__ bout,
           const float* __restrict__ Wlin, const float* __restrict__ blin,
           u16* __restrict__ X, u16* __restrict__ Hbuf,
           u16* __restrict__ vbuf, float* __restrict__ pmax,
           u32* flags, float* __restrict__ out)
{
  __shared__ __align__(16) float S[32768];   // 128 KB: single-round reduction scratch
  const int tid  = threadIdx.x;
  const int wid  = tid >> 6, lane = tid & 63;
  const int lrow = lane & 15, lgrp = lane >> 4;
  const int bid  = blockIdx.x;
  const int g = bid & 3, jb = bid >> 2;      // XCD-clustered group mapping
  const int p0 = g * 64, j0 = jb * 16;
  u32* fgrp = flags + g * 64;
  u32* myflag = fgrp + jb;

  // ---- init: gather X[t=jb][p0..p0+63][:] (write-through); zero own Hbuf[0] chunk
  for (int it = 0; it < 8; ++it) {
    int e = (it * 512 + tid) * 8;
    int row = e >> 9, col = e & 511;
    int tok = paths[(p0 + row) * L_ + jb];
    const float* s = emb + (size_t)tok * IDIM + col;
    st16_coh(X + ((size_t)jb * P_ + p0 + row) * IDIM + col,
             pack8v(*(const float4*)s, *(const float4*)(s + 4)));
  }
  {
    int row = tid >> 3, cp = tid & 7;        // 512 u32 cells = 64 rows x 8 col-pairs
    __hip_atomic_store((u32*)&Hbuf[(size_t)(p0 + row) * H_ + j0 + cp * 2], 0u,
                       __ATOMIC_RELAXED, __HIP_MEMORY_SCOPE_AGENT);
  }
  __syncthreads();                            // drains vmcnt of all waves
  if (tid == 0) set_flag(myflag, 1u);

  // ---- weights into registers: wave wid owns K chunks c = wid + 8*i (i=0..5) ----
  s16x8 breg[6][4];
#pragma unroll
  for (int i = 0; i < 6; ++i) {
    const int kg = (wid + 8 * i) * 32 + lgrp * 8;
#pragma unroll
    for (int fn = 0; fn < 4; ++fn) {
      const int n = fn * H_ + j0 + lrow;
      const float* src = (kg < IDIM) ? (Wih + (size_t)n * IDIM + kg)
                                     : (Whh + (size_t)n * H_ + (kg - IDIM));
      breg[i][fn] = pack8(src);
    }
  }

  // epilogue ownership: waves 0-3 own row-frag fm = wid (16 rows each)
  const int prow = p0 + (wid & 3) * 16 + lgrp * 4;
  int lenr[4]; float biasv[4];
#pragma unroll
  for (int r2 = 0; r2 < 4; ++r2) lenr[r2] = lengths[prow + r2];
#pragma unroll
  for (int fn = 0; fn < 4; ++fn) {
    int n = fn * H_ + j0 + lrow;
    biasv[fn] = bih[n] + bhh[n];
  }
  // consumer-side: length of each A-fragment row this lane loads (row = p0+lrow+16*fm)
  int lenv4[4];
#pragma unroll
  for (int fm = 0; fm < 4; ++fm) lenv4[fm] = lengths[p0 + lrow + 16 * fm];
  float cst[4] = {0.f,0.f,0.f,0.f}, hst[4] = {0.f,0.f,0.f,0.f};

  poll_flags(fgrp, 1u, wid, lane);            // init done (own group)

  const size_t aX = (size_t)(p0 + lrow) * IDIM + lgrp * 8;

  s16x8 fx[2][4];
#define LOADX(T) do { \
    const u16* Xt_ = X + (size_t)(T) * (P_ * IDIM) + aX; \
    _Pragma("unroll") \
    for (int i_ = 0; i_ < 2; ++i_) { \
      const int k0_ = (wid + 8 * i_) * 32; \
      _Pragma("unroll") \
      for (int fm_ = 0; fm_ < 4; ++fm_) \
        fx[i_][fm_] = *(const s16x8*)(Xt_ + (size_t)fm_ * (16 * IDIM) + k0_); \
    } } while (0)

  LOADX(0);

  for (int t = 0; t < L_; ++t) {
    u16* Hw = Hbuf + (size_t)(t + 1) * PH;

    f32x4 acc[4][4];
#pragma unroll
    for (int a = 0; a < 4; ++a)
#pragma unroll
      for (int b = 0; b < 4; ++b)
#pragma unroll
        for (int e = 0; e < 4; ++e) acc[a][b][e] = 0.0f;

    // ---- X phase (pre-poll; hides sibling skew) ----
#pragma unroll
    for (int i = 0; i < 2; ++i)
#pragma unroll
      for (int fm = 0; fm < 4; ++fm)
#pragma unroll
        for (int fn = 0; fn < 4; ++fn)
          acc[fm][fn] = __builtin_amdgcn_mfma_f32_16x16x32_bf16(fx[i][fm], breg[i][fn], acc[fm][fn], 0, 0, 0);

    // ---- wait for Hbuf[t] ----
    poll_flags(fgrp, (u32)(t + 1), wid, lane);

    // ---- H phase: per-row buffer redirect min(t, len) (frozen rows L2-stable) ----
    const u16* hb[4];
#pragma unroll
    for (int fm = 0; fm < 4; ++fm) {
      int bi = (t < lenv4[fm]) ? t : lenv4[fm];
      hb[fm] = Hbuf + (size_t)bi * PH + (size_t)(p0 + lrow + 16 * fm) * H_ + lgrp * 8;
    }
    s16x8 fhA[2][4], fhB[2][4];
#pragma unroll
    for (int i = 0; i < 2; ++i) {
      const int kh = wid * 32 + i * 256;
#pragma unroll
      for (int fm = 0; fm < 4; ++fm)
        fhA[i][fm] = *(const s16x8*)(hb[fm] + kh);
    }
#pragma unroll
    for (int i = 0; i < 2; ++i) {
      const int kh = wid * 32 + 512 + i * 256;
#pragma unroll
      for (int fm = 0; fm < 4; ++fm)
        fhB[i][fm] = *(const s16x8*)(hb[fm] + kh);
    }
#pragma unroll
    for (int i = 0; i < 2; ++i)
#pragma unroll
      for (int fm = 0; fm < 4; ++fm)
#pragma unroll
        for (int fn = 0; fn < 4; ++fn)
          acc[fm][fn] = __builtin_amdgcn_mfma_f32_16x16x32_bf16(fhA[i][fm], breg[2 + i][fn], acc[fm][fn], 0, 0, 0);
    { const int tp1 = (t < L_ - 1) ? (t + 1) : (L_ - 1); LOADX(tp1); }
#pragma unroll
    for (int i = 0; i < 2; ++i)
#pragma unroll
      for (int fm = 0; fm < 4; ++fm)
#pragma unroll
        for (int fn = 0; fn < 4; ++fn)
          acc[fm][fn] = __builtin_amdgcn_mfma_f32_16x16x32_bf16(fhB[i][fm], breg[4 + i][fn], acc[fm][fn], 0, 0, 0);

    // ---- 8-way reduction: SINGLE round over 128 KB LDS ----
    f32x4 red[4];
#pragma unroll
    for (int fm = 0; fm < 4; ++fm)
#pragma unroll
      for (int fn = 0; fn < 4; ++fn)
        *(f32x4*)&S[((wid * 16) + fm * 4 + fn) * 256 + lane * 4] = acc[fm][fn];
    lds_barrier();
    if (wid < 4) {
#pragma unroll
      for (int fn = 0; fn < 4; ++fn) {
        f32x4 v = *(const f32x4*)&S[(wid * 4 + fn) * 256 + lane * 4];
#pragma unroll
        for (int s = 1; s < 8; ++s)
          v += *(const f32x4*)&S[(s * 16 + wid * 4 + fn) * 256 + lane * 4];
        red[fn] = v;
      }
    }
    lds_barrier();                            // S reusable for next step's dump

    // ---- gate epilogue (waves 0-3): active rows only store ----
    if (wid < 4) {
#pragma unroll
      for (int r2 = 0; r2 < 4; ++r2) {
        if (t < lenr[r2]) {
          float gi = red[0][r2] + biasv[0];
          float gf = red[1][r2] + biasv[1];
          float gg = red[2][r2] + biasv[2];
          float go = red[3][r2] + biasv[3];
          float cn = sigf(gf) * cst[r2] + sigf(gi) * tanhf_(gg);
          cst[r2] = cn;
          hst[r2] = sigf(go) * tanhf_(cn);
          st_pair(&Hw[(size_t)(prow + r2) * H_ + j0 + lrow], hst[r2], lane);
        }
      }
    }
    __syncthreads();                          // drain remaining stores before flag
    if (tid == 0) set_flag(myflag, (u32)(t + 2));
  }

  // ================= tail =================
  poll_flags(fgrp, 65u, wid, lane);

  // ---- v = h@Wv^T + bv: read h_final = Hbuf[len[p]] per row ----
  {
    const u16* hpf[4];
#pragma unroll
    for (int fm = 0; fm < 4; ++fm)
      hpf[fm] = Hbuf + (size_t)lenv4[fm] * PH + (size_t)(p0 + lrow + 16 * fm) * H_ + lgrp * 8;
    f32x4 acc2[4];
#pragma unroll
    for (int a = 0; a < 4; ++a)
#pragma unroll
      for (int e = 0; e < 4; ++e) acc2[a][e] = 0.0f;
    const float* wv = Win + (size_t)(2 * H_ + j0 + lrow) * H_;
#pragma unroll
    for (int ic = 0; ic < 4; ++ic) {
      const int k0 = wid * 128 + ic * 32;
      s16x8 fbv = pack8(wv + k0 + lgrp * 8);
#pragma unroll
      for (int fm = 0; fm < 4; ++fm) {
        s16x8 fav = *(const s16x8*)(hpf[fm] + k0);
        acc2[fm] = __builtin_amdgcn_mfma_f32_16x16x32_bf16(fav, fbv, acc2[fm], 0, 0, 0);
      }
    }
#pragma unroll
    for (int fm = 0; fm < 4; ++fm)
      *(f32x4*)&S[(wid * 4 + fm) * 256 + lane * 4] = acc2[fm];
    __syncthreads();
    if (wid < 4) {
      f32x4 rv = *(const f32x4*)&S[(wid) * 256 + lane * 4];
#pragma unroll
      for (int s = 1; s < 8; ++s)
        rv += *(const f32x4*)&S[(s * 4 + wid) * 256 + lane * 4];
      float bvj = bin[2 * H_ + j0 + lrow];
#pragma unroll
      for (int r2 = 0; r2 < 4; ++r2)
        st_pair(&vbuf[(size_t)(prow + r2) * H_ + j0 + lrow], rv[r2] + bvj, lane);
    }
  }
  __syncthreads();
  if (tid == 0) set_flag(myflag, 66u);
  poll_flags(fgrp, 66u, wid, lane);

  // ---- attn = v@Wout^T + bout, per-block max over own 64 rows ----
  {
    const size_t aH = (size_t)(p0 + lrow) * H_ + lgrp * 8;
    f32x4 acc2[4];
#pragma unroll
    for (int a = 0; a < 4; ++a)
#pragma unroll
      for (int e = 0; e < 4; ++e) acc2[a][e] = 0.0f;
    const u16* vp = vbuf + aH;
    const float* wo = Wout + (size_t)(j0 + lrow) * H_;
#pragma unroll
    for (int ic = 0; ic < 4; ++ic) {
      const int k0 = wid * 128 + ic * 32;
      s16x8 fbv = pack8(wo + k0 + lgrp * 8);
#pragma unroll
      for (int fm = 0; fm < 4; ++fm) {
        s16x8 fav = *(const s16x8*)(vp + (size_t)fm * (16 * H_) + k0);
        acc2[fm] = __builtin_amdgcn_mfma_f32_16x16x32_bf16(fav, fbv, acc2[fm], 0, 0, 0);
      }
    }
#pragma unroll
    for (int fm = 0; fm < 4; ++fm)
      *(f32x4*)&S[(wid * 4 + fm) * 256 + lane * 4] = acc2[fm];
    __syncthreads();
    if (wid < 4) {
      f32x4 rv = *(const f32x4*)&S[(wid) * 256 + lane * 4];
#pragma unroll
      for (int s = 1; s < 8; ++s)
        rv += *(const f32x4*)&S[(s * 4 + wid) * 256 + lane * 4];
      float bo = bout[j0 + lrow];
      float m = fmaxf(fmaxf(rv[0], rv[1]), fmaxf(rv[2], rv[3])) + bo;
      __syncthreads();
      S[(wid * 4 + lgrp) * 16 + lrow] = m;
    } else {
      __syncthreads();
    }
    __syncthreads();
    if (tid < 16) {
      float mx = S[tid];
#pragma unroll
      for (int s2 = 1; s2 < 16; ++s2) mx = fmaxf(mx, S[s2 * 16 + tid]);
      __hip_atomic_store(&pmax[(size_t)g * H_ + j0 + tid], mx, __ATOMIC_RELAXED, __HIP_MEMORY_SCOPE_AGENT);
    }
  }
  __syncthreads();
  if (tid == 0) set_flag(myflag, 67u);

  if (bid != 0) return;

  // ---- final: max over groups, 1024->2 dot, sigmoid (512 threads, 2 elems each) ----
  if (wid == 0) {
    for (int g2 = 0; g2 < 4; ++g2) {
      for (;;) {
        u32 f = __hip_atomic_load(&flags[g2 * 64 + lane], __ATOMIC_RELAXED, __HIP_MEMORY_SCOPE_AGENT);
        if (__all((int)(f >= 67u))) break;
        __builtin_amdgcn_s_sleep(1);
      }
    }
  }
  asm volatile("" ::: "memory");
  __syncthreads();
  {
    int j2 = tid * 2;
    float s0 = 0.f, s1 = 0.f;
#pragma unroll
    for (int e = 0; e < 2; ++e) {
      float pv = pmax[j2 + e];
#pragma unroll
      for (int gg2 = 1; gg2 < 4; ++gg2) pv = fmaxf(pv, pmax[gg2 * H_ + j2 + e]);
      s0 += pv * Wlin[j2 + e];
      s1 += pv * Wlin[H_ + j2 + e];
    }
    S[tid] = s0; S[512 + tid] = s1;
    __syncthreads();
    for (int s2 = 256; s2 > 0; s2 >>= 1) {
      if (tid < s2) { S[tid] += S[tid + s2]; S[512 + tid] += S[512 + tid + s2]; }
      __syncthreads();
    }
    if (tid == 0) {
      out[0] = sigf(S[0] + blin[0]);
      out[1] = sigf(S[512] + blin[1]);
    }
  }
}

extern "C" void kernel_launch(void* const* d_in, const int* in_sizes, int n_in,
                              void* d_out, int out_size, void* d_ws, size_t ws_size,
                              hipStream_t stream) {
  const int*   paths   = (const int*)d_in[0];
  const int*   lengths = (const int*)d_in[1];
  const float* emb     = (const float*)d_in[2];
  const float* Wih     = (const float*)d_in[3];
  const float* Whh     = (const float*)d_in[4];
  const float* bih     = (const float*)d_in[5];
  const float* bhh     = (const float*)d_in[6];
  const float* Win     = (const float*)d_in[7];
  const float* bin     = (const float*)d_in[8];
  const float* Wout    = (const float*)d_in[9];
  const float* bout    = (const float*)d_in[10];
  const float* Wlin    = (const float*)d_in[11];
  const float* blin    = (const float*)d_in[12];
  float* out = (float*)d_out;

  char* ws = (char*)d_ws;
  u32*   flags  = (u32*)  (ws);                  //      1,024 (4 groups x 64 packed flags)
  float* pmax   = (float*)(ws + 4096);           //     16,384
  u16*   X      = (u16*)  (ws + 32768);          // 16,777,216
  u16*   Hbuf   = (u16*)  (ws + 16810240);       // 65 x 524,288 = 34,078,720
  u16*   vbuf   = (u16*)  (ws + 50888960);       //    524,288   (total ~51.4 MB)

  hipMemsetAsync(flags, 0, 1024, stream);
  tagger_net<<<256, 512, 0, stream>>>(paths, lengths, emb, Wih, Whh, bih, bhh,
                                      Win, bin, Wout, bout, Wlin, blin,
                                      X, Hbuf, vbuf, pmax, flags, out);
}

// Round 19
// 531.743 us; speedup vs baseline: 1.1297x; 1.1297x over previous
//
#include <hip/hip_runtime.h>
#include <stdint.h>

typedef unsigned short u16;
typedef unsigned int u32;
typedef __attribute__((ext_vector_type(8))) short s16x8;
typedef __attribute__((ext_vector_type(4))) float f32x4;

#define P_ 256
#define L_ 64
#define IDIM 512
#define H_ 1024
#define PH (P_ * H_)

__device__ __forceinline__ u16 f2bf(float f){union{float f;u32 u;}v;v.f=f;u32 u=v.u;return (u16)((u+0x7FFFu+((u>>16)&1u))>>16);}
__device__ __forceinline__ float sigf(float x){return 1.0f/(1.0f+__expf(-x));}
__device__ __forceinline__ float tanhf_(float x){return 1.0f-2.0f/(__expf(2.0f*x)+1.0f);}

__device__ __forceinline__ s16x8 pack8v(float4 a, float4 b){
  s16x8 r;
  r[0]=(short)f2bf(a.x); r[1]=(short)f2bf(a.y); r[2]=(short)f2bf(a.z); r[3]=(short)f2bf(a.w);
  r[4]=(short)f2bf(b.x); r[5]=(short)f2bf(b.y); r[6]=(short)f2bf(b.z); r[7]=(short)f2bf(b.w);
  return r;
}
__device__ __forceinline__ s16x8 pack8(const float* s){
  return pack8v(*(const float4*)s, *(const float4*)(s+4));
}
// 16B write-through store (bypasses L2 -> coherent at IF$)
__device__ __forceinline__ void st16_coh(u16* addr, s16x8 v){
  asm volatile("global_store_dwordx4 %0, %1, off sc0 sc1" :: "v"(addr), "v"(v) : "memory");
}
// paired 2-lane bf16 -> one 32-bit write-through store
__device__ __forceinline__ void st_pair(u16* addr, float hv, int lane){
  u32 b = (u32)f2bf(hv);
  u32 other = __shfl_xor(b, 1);
  if ((lane & 1) == 0) {
    u32 w = b | (other << 16);
    __hip_atomic_store((u32*)addr, w, __ATOMIC_RELAXED, __HIP_MEMORY_SCOPE_AGENT);
  }
}
__device__ __forceinline__ void set_flag(u32* f, u32 v){
  __hip_atomic_store(f, v, __ATOMIC_RELAXED, __HIP_MEMORY_SCOPE_AGENT);
}
// block-wide poll: wave0 polls 64 packed flags (one coalesced load/iter) + syncthreads
__device__ __forceinline__ void poll_flags(u32* fg, u32 target, int wid, int lane){
  if (wid == 0) {
    for (;;) {
      u32 f = __hip_atomic_load(&fg[lane], __ATOMIC_RELAXED, __HIP_MEMORY_SCOPE_AGENT);
      if (__all((int)(f >= target))) break;
      __builtin_amdgcn_s_sleep(1);
    }
  }
  asm volatile("" ::: "memory");
  __syncthreads();
}
// lgkm-only barrier (LDS writes drained; VMEM loads stay in flight) — rule #18 fenced
__device__ __forceinline__ void lds_barrier(){
  asm volatile("s_waitcnt lgkmcnt(0)" ::: "memory");
  __builtin_amdgcn_sched_barrier(0);
  __builtin_amdgcn_s_barrier();
  __builtin_amdgcn_sched_barrier(0);
}

// Persistent kernel: 256 blocks x 512 threads = 4 path-groups x 64 unit-blocks.
// 8 waves/block, K-split 192/wave (breg 96 VGPR). XCD-clustered (g = bid&3).
// 128 KB single-round reduce; 3 block joins per step (redundant post-read barrier
// removed: epilogue-sync + next poll-sync already order S-reads before next dump).
__global__ void __launch_bounds__(512, 1)
tagger_net(const int* __restrict__ paths, const int* __restrict__ lengths,
           const float* __restrict__ emb,
           const float* __restrict__ Wih, const float* __restrict__ Whh,
           const float* __restrict__ bih, const float* __restrict__ bhh,
           const float* __restrict__ Win, const float* __restrict__ bin,
           const float* __restrict__ Wout, const float* __restrict__ bout,
           const float* __restrict__ Wlin, const float* __restrict__ blin,
           u16* __restrict__ X, u16* __restrict__ Hbuf,
           u16* __restrict__ vbuf, float* __restrict__ pmax,
           u32* flags, float* __restrict__ out)
{
  __shared__ __align__(16) float S[32768];   // 128 KB: single-round reduction scratch
  const int tid  = threadIdx.x;
  const int wid  = tid >> 6, lane = tid & 63;
  const int lrow = lane & 15, lgrp = lane >> 4;
  const int bid  = blockIdx.x;
  const int g = bid & 3, jb = bid >> 2;      // XCD-clustered group mapping
  const int p0 = g * 64, j0 = jb * 16;
  u32* fgrp = flags + g * 64;
  u32* myflag = fgrp + jb;

  // ---- init: gather X[t=jb][p0..p0+63][:] (write-through); zero own Hbuf[0] chunk
  for (int it = 0; it < 8; ++it) {
    int e = (it * 512 + tid) * 8;
    int row = e >> 9, col = e & 511;
    int tok = paths[(p0 + row) * L_ + jb];
    const float* s = emb + (size_t)tok * IDIM + col;
    st16_coh(X + ((size_t)jb * P_ + p0 + row) * IDIM + col,
             pack8v(*(const float4*)s, *(const float4*)(s + 4)));
  }
  {
    int row = tid >> 3, cp = tid & 7;        // 512 u32 cells = 64 rows x 8 col-pairs
    __hip_atomic_store((u32*)&Hbuf[(size_t)(p0 + row) * H_ + j0 + cp * 2], 0u,
                       __ATOMIC_RELAXED, __HIP_MEMORY_SCOPE_AGENT);
  }
  __syncthreads();                            // drains vmcnt of all waves
  if (tid == 0) set_flag(myflag, 1u);

  // ---- weights into registers: wave wid owns K chunks c = wid + 8*i (i=0..5) ----
  // i=0,1 -> X chunks (k<512); i=2..5 -> H chunks
  s16x8 breg[6][4];
#pragma unroll
  for (int i = 0; i < 6; ++i) {
    const int kg = (wid + 8 * i) * 32 + lgrp * 8;
#pragma unroll
    for (int fn = 0; fn < 4; ++fn) {
      const int n = fn * H_ + j0 + lrow;
      const float* src = (kg < IDIM) ? (Wih + (size_t)n * IDIM + kg)
                                     : (Whh + (size_t)n * H_ + (kg - IDIM));
      breg[i][fn] = pack8(src);
    }
  }

  // epilogue ownership: waves 0-3 own row-frag fm = wid (16 rows each)
  const int prow = p0 + (wid & 3) * 16 + lgrp * 4;
  int lenr[4]; float biasv[4];
#pragma unroll
  for (int r2 = 0; r2 < 4; ++r2) lenr[r2] = lengths[prow + r2];
#pragma unroll
  for (int fn = 0; fn < 4; ++fn) {
    int n = fn * H_ + j0 + lrow;
    biasv[fn] = bih[n] + bhh[n];
  }
  float cst[4] = {0.f,0.f,0.f,0.f}, hst[4] = {0.f,0.f,0.f,0.f};

  poll_flags(fgrp, 1u, wid, lane);            // init done (own group)

  const size_t aX = (size_t)(p0 + lrow) * IDIM + lgrp * 8;
  const size_t aH = (size_t)(p0 + lrow) * H_   + lgrp * 8;

  s16x8 fx[2][4];
#define LOADX(T) do { \
    const u16* Xt_ = X + (size_t)(T) * (P_ * IDIM) + aX; \
    _Pragma("unroll") \
    for (int i_ = 0; i_ < 2; ++i_) { \
      const int k0_ = (wid + 8 * i_) * 32; \
      _Pragma("unroll") \
      for (int fm_ = 0; fm_ < 4; ++fm_) \
        fx[i_][fm_] = *(const s16x8*)(Xt_ + (size_t)fm_ * (16 * IDIM) + k0_); \
    } } while (0)

  LOADX(0);

  for (int t = 0; t < L_; ++t) {
    const u16* Hr = Hbuf + (size_t)t * PH;
    u16*       Hw = Hbuf + (size_t)(t + 1) * PH;

    f32x4 acc[4][4];
#pragma unroll
    for (int a = 0; a < 4; ++a)
#pragma unroll
      for (int b = 0; b < 4; ++b)
#pragma unroll
        for (int e = 0; e < 4; ++e) acc[a][b][e] = 0.0f;

    // ---- X phase (pre-poll; hides sibling skew) ----
#pragma unroll
    for (int i = 0; i < 2; ++i)
#pragma unroll
      for (int fm = 0; fm < 4; ++fm)
#pragma unroll
        for (int fn = 0; fn < 4; ++fn)
          acc[fm][fn] = __builtin_amdgcn_mfma_f32_16x16x32_bf16(fx[i][fm], breg[i][fn], acc[fm][fn], 0, 0, 0);

    // ---- wait for Hbuf[t] ----
    poll_flags(fgrp, (u32)(t + 1), wid, lane);

    // ---- H phase: issue ALL 4 chunk-batches (VGPR headroom), then MFMA ----
    const u16* Hp = Hr + aH;
    s16x8 fhA[2][4], fhB[2][4];
#pragma unroll
    for (int i = 0; i < 2; ++i) {
      const int kh = wid * 32 + i * 256;      // chunks kh = wid*32 + {0,256}
#pragma unroll
      for (int fm = 0; fm < 4; ++fm)
        fhA[i][fm] = *(const s16x8*)(Hp + (size_t)fm * (16 * H_) + kh);
    }
#pragma unroll
    for (int i = 0; i < 2; ++i) {
      const int kh = wid * 32 + 512 + i * 256; // chunks kh = wid*32 + {512,768}
#pragma unroll
      for (int fm = 0; fm < 4; ++fm)
        fhB[i][fm] = *(const s16x8*)(Hp + (size_t)fm * (16 * H_) + kh);
    }
#pragma unroll
    for (int i = 0; i < 2; ++i)
#pragma unroll
      for (int fm = 0; fm < 4; ++fm)
#pragma unroll
        for (int fn = 0; fn < 4; ++fn)
          acc[fm][fn] = __builtin_amdgcn_mfma_f32_16x16x32_bf16(fhA[i][fm], breg[2 + i][fn], acc[fm][fn], 0, 0, 0);
    { const int tp1 = (t < L_ - 1) ? (t + 1) : (L_ - 1); LOADX(tp1); }
#pragma unroll
    for (int i = 0; i < 2; ++i)
#pragma unroll
      for (int fm = 0; fm < 4; ++fm)
#pragma unroll
        for (int fn = 0; fn < 4; ++fn)
          acc[fm][fn] = __builtin_amdgcn_mfma_f32_16x16x32_bf16(fhB[i][fm], breg[4 + i][fn], acc[fm][fn], 0, 0, 0);

    // ---- 8-way reduction: SINGLE round over 128 KB LDS ----
    f32x4 red[4];
#pragma unroll
    for (int fm = 0; fm < 4; ++fm)
#pragma unroll
      for (int fn = 0; fn < 4; ++fn)
        *(f32x4*)&S[((wid * 16) + fm * 4 + fn) * 256 + lane * 4] = acc[fm][fn];
    lds_barrier();
    if (wid < 4) {
#pragma unroll
      for (int fn = 0; fn < 4; ++fn) {
        f32x4 v = *(const f32x4*)&S[(wid * 4 + fn) * 256 + lane * 4];
#pragma unroll
        for (int s = 1; s < 8; ++s)
          v += *(const f32x4*)&S[(s * 16 + wid * 4 + fn) * 256 + lane * 4];
        red[fn] = v;
      }
    }
    // NOTE: no barrier here. S-reads are ordered before the next dump by the
    // epilogue __syncthreads below + the poll __syncthreads at t+1.

    // ---- gate epilogue (waves 0-3), write-through H ----
    if (wid < 4) {
#pragma unroll
      for (int r2 = 0; r2 < 4; ++r2) {
        if (t < lenr[r2]) {
          float gi = red[0][r2] + biasv[0];
          float gf = red[1][r2] + biasv[1];
          float gg = red[2][r2] + biasv[2];
          float go = red[3][r2] + biasv[3];
          float cn = sigf(gf) * cst[r2] + sigf(gi) * tanhf_(gg);
          cst[r2] = cn;
          hst[r2] = sigf(go) * tanhf_(cn);
        }
        st_pair(&Hw[(size_t)(prow + r2) * H_ + j0 + lrow], hst[r2], lane);
      }
    }
    __syncthreads();                          // drain all stores before flag
    if (tid == 0) set_flag(myflag, (u32)(t + 2));
  }

  // ================= tail =================
  const u16* hfin = Hbuf + (size_t)L_ * PH;
  poll_flags(fgrp, 65u, wid, lane);

  // ---- v = h@Wv^T + bv (8-way K-split, single 32 KB dump) ----
  {
    f32x4 acc2[4];
#pragma unroll
    for (int a = 0; a < 4; ++a)
#pragma unroll
      for (int e = 0; e < 4; ++e) acc2[a][e] = 0.0f;
    const u16* hp = hfin + aH;
    const float* wv = Win + (size_t)(2 * H_ + j0 + lrow) * H_;
#pragma unroll
    for (int ic = 0; ic < 4; ++ic) {
      const int k0 = wid * 128 + ic * 32;
      s16x8 fbv = pack8(wv + k0 + lgrp * 8);
#pragma unroll
      for (int fm = 0; fm < 4; ++fm) {
        s16x8 fav = *(const s16x8*)(hp + (size_t)fm * (16 * H_) + k0);
        acc2[fm] = __builtin_amdgcn_mfma_f32_16x16x32_bf16(fav, fbv, acc2[fm], 0, 0, 0);
      }
    }
#pragma unroll
    for (int fm = 0; fm < 4; ++fm)
      *(f32x4*)&S[(wid * 4 + fm) * 256 + lane * 4] = acc2[fm];
    __syncthreads();
    if (wid < 4) {
      f32x4 rv = *(const f32x4*)&S[(wid) * 256 + lane * 4];
#pragma unroll
      for (int s = 1; s < 8; ++s)
        rv += *(const f32x4*)&S[(s * 4 + wid) * 256 + lane * 4];
      float bvj = bin[2 * H_ + j0 + lrow];
#pragma unroll
      for (int r2 = 0; r2 < 4; ++r2)
        st_pair(&vbuf[(size_t)(prow + r2) * H_ + j0 + lrow], rv[r2] + bvj, lane);
    }
  }
  __syncthreads();
  if (tid == 0) set_flag(myflag, 66u);
  poll_flags(fgrp, 66u, wid, lane);

  // ---- attn = v@Wout^T + bout, per-block max over own 64 rows ----
  {
    f32x4 acc2[4];
#pragma unroll
    for (int a = 0; a < 4; ++a)
#pragma unroll
      for (int e = 0; e < 4; ++e) acc2[a][e] = 0.0f;
    const u16* vp = vbuf + aH;
    const float* wo = Wout + (size_t)(j0 + lrow) * H_;
#pragma unroll
    for (int ic = 0; ic < 4; ++ic) {
      const int k0 = wid * 128 + ic * 32;
      s16x8 fbv = pack8(wo + k0 + lgrp * 8);
#pragma unroll
      for (int fm = 0; fm < 4; ++fm) {
        s16x8 fav = *(const s16x8*)(vp + (size_t)fm * (16 * H_) + k0);
        acc2[fm] = __builtin_amdgcn_mfma_f32_16x16x32_bf16(fav, fbv, acc2[fm], 0, 0, 0);
      }
    }
#pragma unroll
    for (int fm = 0; fm < 4; ++fm)
      *(f32x4*)&S[(wid * 4 + fm) * 256 + lane * 4] = acc2[fm];
    __syncthreads();
    if (wid < 4) {
      f32x4 rv = *(const f32x4*)&S[(wid) * 256 + lane * 4];
#pragma unroll
      for (int s = 1; s < 8; ++s)
        rv += *(const f32x4*)&S[(s * 4 + wid) * 256 + lane * 4];
      float bo = bout[j0 + lrow];
      float m = fmaxf(fmaxf(rv[0], rv[1]), fmaxf(rv[2], rv[3])) + bo;
      __syncthreads();
      S[(wid * 4 + lgrp) * 16 + lrow] = m;
    } else {
      __syncthreads();
    }
    __syncthreads();
    if (tid < 16) {
      float mx = S[tid];
#pragma unroll
      for (int s2 = 1; s2 < 16; ++s2) mx = fmaxf(mx, S[s2 * 16 + tid]);
      __hip_atomic_store(&pmax[(size_t)g * H_ + j0 + tid], mx, __ATOMIC_RELAXED, __HIP_MEMORY_SCOPE_AGENT);
    }
  }
  __syncthreads();
  if (tid == 0) set_flag(myflag, 67u);

  if (bid != 0) return;

  // ---- final: max over groups, 1024->2 dot, sigmoid (512 threads, 2 elems each) ----
  if (wid == 0) {
    for (int g2 = 0; g2 < 4; ++g2) {
      for (;;) {
        u32 f = __hip_atomic_load(&flags[g2 * 64 + lane], __ATOMIC_RELAXED, __HIP_MEMORY_SCOPE_AGENT);
        if (__all((int)(f >= 67u))) break;
        __builtin_amdgcn_s_sleep(1);
      }
    }
  }
  asm volatile("" ::: "memory");
  __syncthreads();
  {
    int j2 = tid * 2;
    float s0 = 0.f, s1 = 0.f;
#pragma unroll
    for (int e = 0; e < 2; ++e) {
      float pv = pmax[j2 + e];
#pragma unroll
      for (int gg2 = 1; gg2 < 4; ++gg2) pv = fmaxf(pv, pmax[gg2 * H_ + j2 + e]);
      s0 += pv * Wlin[j2 + e];
      s1 += pv * Wlin[H_ + j2 + e];
    }
    S[tid] = s0; S[512 + tid] = s1;
    __syncthreads();
    for (int s2 = 256; s2 > 0; s2 >>= 1) {
      if (tid < s2) { S[tid] += S[tid + s2]; S[512 + tid] += S[512 + tid + s2]; }
      __syncthreads();
    }
    if (tid == 0) {
      out[0] = sigf(S[0] + blin[0]);
      out[1] = sigf(S[512] + blin[1]);
    }
  }
}

extern "C" void kernel_launch(void* const* d_in, const int* in_sizes, int n_in,
                              void* d_out, int out_size, void* d_ws, size_t ws_size,
                              hipStream_t stream) {
  const int*   paths   = (const int*)d_in[0];
  const int*   lengths = (const int*)d_in[1];
  const float* emb     = (const float*)d_in[2];
  const float* Wih     = (const float*)d_in[3];
  const float* Whh     = (const float*)d_in[4];
  const float* bih     = (const float*)d_in[5];
  const float* bhh     = (const float*)d_in[6];
  const float* Win     = (const float*)d_in[7];
  const float* bin     = (const float*)d_in[8];
  const float* Wout    = (const float*)d_in[9];
  const float* bout    = (const float*)d_in[10];
  const float* Wlin    = (const float*)d_in[11];
  const float* blin    = (const float*)d_in[12];
  float* out = (float*)d_out;

  char* ws = (char*)d_ws;
  u32*   flags  = (u32*)  (ws);                  //      1,024 (4 groups x 64 packed flags)
  float* pmax   = (float*)(ws + 4096);           //     16,384
  u16*   X      = (u16*)  (ws + 32768);          // 16,777,216
  u16*   Hbuf   = (u16*)  (ws + 16810240);       // 65 x 524,288 = 34,078,720
  u16*   vbuf   = (u16*)  (ws + 50888960);       //    524,288   (total ~51.4 MB)

  hipMemsetAsync(flags, 0, 1024, stream);
  tagger_net<<<256, 512, 0, stream>>>(paths, lengths, emb, Wih, Whh, bih, bhh,
                                      Win, bin, Wout, bout, Wlin, blin,
                                      X, Hbuf, vbuf, pmax, flags, out);
}